// Round 12
// baseline (876.003 us; speedup 1.0000x reference)
//
#include <hip/hip_runtime.h>
#include <math.h>
#include <type_traits>

// ---------- bf16 helpers (intermediate buffers only; I/O is fp32) ----------

__device__ __forceinline__ float bf2f(unsigned short u) {
    union { unsigned int i; float f; } v; v.i = ((unsigned int)u) << 16; return v.f;
}
__device__ __forceinline__ unsigned short f2bf(float f) {
    union { float f_; unsigned int i; } v; v.f_ = f;
    unsigned int x = v.i;
    return (unsigned short)((x + 0x7fffu + ((x >> 16) & 1u)) >> 16);  // RNE
}
__device__ __forceinline__ float sigm(float x) { return 1.f / (1.f + expf(-x)); }

typedef __attribute__((ext_vector_type(8))) short short8;
typedef __attribute__((ext_vector_type(4))) float f32x4;

// ---------------- CSR build ----------------

__global__ void k_count(const int* __restrict__ dst, int* __restrict__ indeg, int E) {
    int i = blockIdx.x * 256 + threadIdx.x;
    if (i < E) atomicAdd(&indeg[dst[i]], 1);
}

// scan phase 1 + dinv fused
__global__ __launch_bounds__(1024) void k_scan1(const int* __restrict__ in, int* __restrict__ out,
                                                int* __restrict__ bsum, float* __restrict__ dinv,
                                                int N) {
    __shared__ int sd[1024];
    int tid = threadIdx.x;
    int i = blockIdx.x * 1024 + tid;
    int v = (i < N) ? in[i] : 0;
    if (i < N) dinv[i] = rsqrtf((float)v + 1.0f);
    sd[tid] = v;
    __syncthreads();
    for (int s = 1; s < 1024; s <<= 1) {
        int t = (tid >= s) ? sd[tid - s] : 0;
        __syncthreads();
        sd[tid] += t;
        __syncthreads();
    }
    if (i < N) out[i] = sd[tid] - v;
    if (tid == 1023) bsum[blockIdx.x] = sd[1023];
}

__global__ void k_scan2(int* __restrict__ bsum, int nb) {
    if (threadIdx.x == 0 && blockIdx.x == 0) {
        int acc = 0;
        for (int b = 0; b < nb; ++b) { int t = bsum[b]; bsum[b] = acc; acc += t; }
        bsum[nb] = acc;
    }
}

__global__ __launch_bounds__(1024) void k_scan3(int* __restrict__ off, const int* __restrict__ bsum,
                                                int N, int nb) {
    int i = blockIdx.x * 1024 + threadIdx.x;
    if (i < N) off[i] += bsum[i >> 10];
    else if (i == N) off[N] = bsum[nb];
}

// packed edge records: cpack[p] = {src, bits(dinv[src]*dinv[dst])}
__global__ void k_fill(const int* __restrict__ src, const int* __restrict__ dst,
                       const float* __restrict__ dinv, const int* __restrict__ off,
                       int* __restrict__ cursor, int2* __restrict__ cpack, int E) {
    int i = blockIdx.x * 256 + threadIdx.x;
    if (i >= E) return;
    int d = dst[i], s = src[i];
    int p = off[d] + atomicAdd(&cursor[d], 1);
    int2 rec; rec.x = s; rec.y = __float_as_int(dinv[s] * dinv[d]);
    cpack[p] = rec;
}

// ---------------- weight transpose+convert: Wt[n][k] = bf16(W[k][n]) ----------------

__global__ void k_transpose(const float* __restrict__ W, unsigned short* __restrict__ Wt,
                            int K, int Nc) {
    int i = blockIdx.x * 256 + threadIdx.x;
    if (i < K * Nc) {
        int k = i / Nc, n = i - k * Nc;
        Wt[(size_t)n * K + k] = f2bf(W[i]);
    }
}

// ---------------- aggregation v4: multi-edge gathers + shfl-broadcast metadata ----
// One wave per node. Metadata for a whole round loaded once, lane-distributed
// (coalesced int2), broadcast by __shfl. Row gathers split across lane groups
// so each load instruction covers multiple edges. Tail slots clamp to 'last'
// (same row -> cache-hot) with weight 0.

// L1: F=32 fp32 in (128 B rows). 8 lanes/edge, float4/lane; 8 edges per inst,
// 64 edges per round. Merge: shfl_xor 8/16/32.
__global__ __launch_bounds__(256) void k_aggL1(
        const float* __restrict__ Hin, const float* __restrict__ dinv,
        const int* __restrict__ off, const int2* __restrict__ cpack,
        unsigned short* __restrict__ out, int N) {
    int wave = (int)((blockIdx.x * 256u + threadIdx.x) >> 6);
    int lane = threadIdx.x & 63;
    if (wave >= N) return;
    int g = lane >> 3, sub = lane & 7;
    int s0 = off[wave], s1 = off[wave + 1];
    int last = s1 - 1;
    float acc[4] = {0.f, 0.f, 0.f, 0.f};
    for (int e = s0; e < s1; e += 64) {
        int ee = e + lane;
        int ec = ee <= last ? ee : last;
        int2 md = cpack[ec];
        int   mi = md.x;
        float mw = (ee <= last) ? __int_as_float(md.y) : 0.f;
        #pragma unroll
        for (int j = 0; j < 8; ++j) {
            int slot = j * 8 + g;
            int   idx = __shfl(mi, slot, 64);
            float w   = __shfl(mw, slot, 64);
            float4 d = *(const float4*)(Hin + (size_t)idx * 32 + sub * 4);
            acc[0] += d.x * w; acc[1] += d.y * w; acc[2] += d.z * w; acc[3] += d.w * w;
        }
    }
    #pragma unroll
    for (int m = 8; m <= 32; m <<= 1) {
        #pragma unroll
        for (int k = 0; k < 4; ++k) acc[k] += __shfl_xor(acc[k], m, 64);
    }
    if (lane < 8) {
        float sn = dinv[wave]; sn *= sn;
        float4 s = *(const float4*)(Hin + (size_t)wave * 32 + lane * 4);
        ushort4 o;
        o.x = f2bf(acc[0] + s.x * sn); o.y = f2bf(acc[1] + s.y * sn);
        o.z = f2bf(acc[2] + s.z * sn); o.w = f2bf(acc[3] + s.w * sn);
        *(ushort4*)(out + (size_t)wave * 32 + lane * 4) = o;
    }
}

// L2: F=128 bf16 (256 B rows). 16 lanes/edge, 16 B/lane; 4 edges per inst,
// 32 edges per round. Merge: shfl_xor 16/32.
__global__ __launch_bounds__(256) void k_aggL2(
        const unsigned short* __restrict__ Hin, const float* __restrict__ dinv,
        const int* __restrict__ off, const int2* __restrict__ cpack,
        unsigned short* __restrict__ out, int N) {
    int wave = (int)((blockIdx.x * 256u + threadIdx.x) >> 6);
    int lane = threadIdx.x & 63;
    if (wave >= N) return;
    int g = lane >> 4, sub = lane & 15;
    int s0 = off[wave], s1 = off[wave + 1];
    int last = s1 - 1;
    float acc[8];
    #pragma unroll
    for (int k = 0; k < 8; ++k) acc[k] = 0.f;
    for (int e = s0; e < s1; e += 32) {
        int ee = e + (lane & 31);
        int ec = ee <= last ? ee : last;
        int2 md = cpack[ec];
        int   mi = md.x;
        float mw = (ee <= last) ? __int_as_float(md.y) : 0.f;
        #pragma unroll
        for (int j = 0; j < 8; ++j) {
            int slot = j * 4 + g;           // 0..31
            int   idx = __shfl(mi, slot, 64);
            float w   = __shfl(mw, slot, 64);
            short8 d = *(const short8*)(Hin + (size_t)idx * 128 + sub * 8);
            #pragma unroll
            for (int k = 0; k < 8; ++k) acc[k] += bf2f((unsigned short)d[k]) * w;
        }
    }
    #pragma unroll
    for (int k = 0; k < 8; ++k) acc[k] += __shfl_xor(acc[k], 16, 64);
    #pragma unroll
    for (int k = 0; k < 8; ++k) acc[k] += __shfl_xor(acc[k], 32, 64);
    if (lane < 16) {
        float sn = dinv[wave]; sn *= sn;
        short8 s = *(const short8*)(Hin + (size_t)wave * 128 + lane * 8);
        short8 o;
        #pragma unroll
        for (int k = 0; k < 8; ++k)
            o[k] = (short)f2bf(acc[k] + bf2f((unsigned short)s[k]) * sn);
        *(short8*)(out + (size_t)wave * 128 + lane * 8) = o;
    }
}

// L3: F=256 bf16 (512 B rows). 32 lanes/edge, 16 B/lane; 2 edges per inst,
// 16 edges per round. Merge: shfl_xor 32.
__global__ __launch_bounds__(256) void k_aggL3(
        const unsigned short* __restrict__ Hin, const float* __restrict__ dinv,
        const int* __restrict__ off, const int2* __restrict__ cpack,
        unsigned short* __restrict__ out, int N) {
    int wave = (int)((blockIdx.x * 256u + threadIdx.x) >> 6);
    int lane = threadIdx.x & 63;
    if (wave >= N) return;
    int half = lane >> 5, sub = lane & 31;
    int s0 = off[wave], s1 = off[wave + 1];
    int last = s1 - 1;
    float acc[8];
    #pragma unroll
    for (int k = 0; k < 8; ++k) acc[k] = 0.f;
    for (int e = s0; e < s1; e += 16) {
        int ee = e + (lane & 15);
        int ec = ee <= last ? ee : last;
        int2 md = cpack[ec];
        int   mi = md.x;
        float mw = (ee <= last) ? __int_as_float(md.y) : 0.f;
        #pragma unroll
        for (int j = 0; j < 8; ++j) {
            int slot = j * 2 + half;        // 0..15
            int   idx = __shfl(mi, slot, 64);
            float w   = __shfl(mw, slot, 64);
            short8 d = *(const short8*)(Hin + (size_t)idx * 256 + sub * 8);
            #pragma unroll
            for (int k = 0; k < 8; ++k) acc[k] += bf2f((unsigned short)d[k]) * w;
        }
    }
    #pragma unroll
    for (int k = 0; k < 8; ++k) acc[k] += __shfl_xor(acc[k], 32, 64);
    if (half == 0) {
        float sn = dinv[wave]; sn *= sn;
        short8 s = *(const short8*)(Hin + (size_t)wave * 256 + sub * 8);
        short8 o;
        #pragma unroll
        for (int k = 0; k < 8; ++k)
            o[k] = (short)f2bf(acc[k] + bf2f((unsigned short)s[k]) * sn);
        *(short8*)(out + (size_t)wave * 256 + sub * 8) = o;
    }
}

// ---------------- A-stationary MFMA GEMM body, LDS-staged B (R9-proven) ------
// NOTE: sbat/pacc init requires __syncthreads before gmin/fast read (r8 crash).

template <int K, int NC, int POOL>
__device__ __forceinline__ void gemm_body(
        const unsigned short* __restrict__ A, const unsigned short* __restrict__ Wt,
        const float* __restrict__ bias, unsigned short* __restrict__ C,
        float* __restrict__ pooled, const int* __restrict__ batch, int M) {
    constexpr int KST = K / 32;
    constexpr int NT = NC / 64;
    constexpr int CH = K / 32;
    __shared__ short8 sB[4 * KST * 64];
    __shared__ float pacc[POOL ? 2 : 1][POOL ? NC : 1];
    __shared__ int sbat[POOL ? 64 : 1];
    int tid = threadIdx.x;
    int lane = tid & 63, wv = tid >> 6;
    int r = lane & 15, q = lane >> 4;
    int rowB0 = blockIdx.x * 64;
    int row0 = rowB0 + wv * 16;

    int gmin = 0; bool fast = false;
    if (POOL) {
        if (tid < 64) {
            int rr = rowB0 + tid; if (rr > M - 1) rr = M - 1;
            sbat[tid] = batch[rr];
        }
        for (int i = tid; i < 2 * NC; i += 256) pacc[i / NC][i % NC] = 0.f;
        __syncthreads();
        gmin = sbat[0]; fast = (sbat[63] - gmin) <= 1;
    }

    int rowA = row0 + r; if (rowA > M - 1) rowA = M - 1;
    const short8* Ap = (const short8*)(A + (size_t)rowA * K) + q;
    short8 aF[KST];
    #pragma unroll
    for (int kc = 0; kc < KST; ++kc) aF[kc] = Ap[kc * 4];

    int sn = tid & 63;
    short8 stage[CH];
    {
        const short8* W8 = (const short8*)(Wt + (size_t)sn * K);
        #pragma unroll
        for (int i = 0; i < CH; ++i) {
            int kq = (i * 256 + tid) >> 6;
            stage[i] = W8[kq];
        }
    }
    int st = (sn >> 4) * (KST * 64) + (sn & 15);

    for (int t = 0; t < NT; ++t) {
        __syncthreads();
        #pragma unroll
        for (int i = 0; i < CH; ++i) {
            int kq = (i * 256 + tid) >> 6;
            sB[st + (kq >> 2) * 64 + (kq & 3) * 16] = stage[i];
        }
        __syncthreads();
        if (t + 1 < NT) {
            const short8* W8 = (const short8*)(Wt + (size_t)((t + 1) * 64 + sn) * K);
            #pragma unroll
            for (int i = 0; i < CH; ++i) {
                int kq = (i * 256 + tid) >> 6;
                stage[i] = W8[kq];
            }
        }
        int col0 = t * 64;
        f32x4 acc[4] = {{0.f,0.f,0.f,0.f},{0.f,0.f,0.f,0.f},{0.f,0.f,0.f,0.f},{0.f,0.f,0.f,0.f}};
        #pragma unroll
        for (int kc = 0; kc < KST; ++kc) {
            #pragma unroll
            for (int tt = 0; tt < 4; ++tt) {
                short8 b = sB[(tt * KST + kc) * 64 + lane];
                acc[tt] = __builtin_amdgcn_mfma_f32_16x16x32_bf16(aF[kc], b, acc[tt], 0, 0, 0);
            }
        }
        #pragma unroll
        for (int tt = 0; tt < 4; ++tt) {
            int col = col0 + tt * 16 + r;
            float bv = bias[col];
            #pragma unroll
            for (int j = 0; j < 4; ++j) {
                int row = row0 + q * 4 + j;
                if (row < M) {
                    float v = fmaxf(acc[tt][j] + bv, 0.f);
                    if (POOL) {
                        int g = sbat[row - rowB0];
                        if (fast) atomicAdd(&pacc[g - gmin][col], v);
                        else      atomicAdd(&pooled[(size_t)g * NC + col], v);
                    } else {
                        C[(size_t)row * NC + col] = f2bf(v);
                    }
                }
            }
        }
    }
    if (POOL) {
        __syncthreads();
        if (fast) {
            for (int i = tid; i < 2 * NC; i += 256) {
                int gg = i / NC, col = i % NC;
                if (gmin + gg < 64 || gg == 0)
                    atomicAdd(&pooled[(size_t)(gmin + gg) * NC + col], pacc[gg][col]);
            }
        }
    }
}

__global__ __launch_bounds__(256, 4) void k_gemmL1(
        const unsigned short* __restrict__ A, const unsigned short* __restrict__ Wt,
        const float* __restrict__ bias, unsigned short* __restrict__ C, int M) {
    gemm_body<32, 128, 0>(A, Wt, bias, C, nullptr, nullptr, M);
}

__global__ __launch_bounds__(256, 4) void k_gemmL2(
        const unsigned short* __restrict__ A, const unsigned short* __restrict__ Wt,
        const float* __restrict__ bias, unsigned short* __restrict__ C, int M) {
    gemm_body<128, 256, 0>(A, Wt, bias, C, nullptr, nullptr, M);
}

__global__ __launch_bounds__(256, 4) void k_gemmL3pool(
        const unsigned short* __restrict__ A, const unsigned short* __restrict__ Wt,
        const float* __restrict__ bias, float* __restrict__ pooled,
        const int* __restrict__ batch, int M) {
    gemm_body<256, 512, 1>(A, Wt, bias, nullptr, pooled, batch, M);
}

// ---------------- graph segment bounds (batch sorted) ----------------

__global__ void k_bounds(const int* __restrict__ batch, int* __restrict__ gstart,
                         int* __restrict__ gend, int N) {
    int i = blockIdx.x * 256 + threadIdx.x;
    if (i >= N) return;
    int g = batch[i];
    if (i == 0 || batch[i - 1] != g) gstart[g] = i;
    if (i == N - 1 || batch[i + 1] != g) gend[g] = i + 1;
}

// ---------------- fused head (all fp32): mean + LSTM0 + LSTM1 + projection ----------------
// h0=c0=0 => gates = x @ Wih.T + bih + bhh; f-gate dead; c = i*g; h = o*tanh(c)

__device__ __forceinline__ float dotf(const float* __restrict__ w,
                                      const float* __restrict__ x, int K) {
    float a = 0.f;
    for (int k = 0; k < K; k += 4) {
        float4 wv = *(const float4*)(w + k);
        a += wv.x * x[k] + wv.y * x[k + 1] + wv.z * x[k + 2] + wv.w * x[k + 3];
    }
    return a;
}

__global__ __launch_bounds__(256) void k_head(
        const float* __restrict__ pooledSum,
        const int* __restrict__ gstart, const int* __restrict__ gend,
        const float* __restrict__ Wih0, const float* __restrict__ bih0,
        const float* __restrict__ bhh0,
        const float* __restrict__ Wih1, const float* __restrict__ bih1,
        const float* __restrict__ bhh1,
        const float* __restrict__ Wp, const float* __restrict__ bp,
        float* __restrict__ out) {
    __shared__ float sx[512];
    __shared__ float sh[256];
    int g = blockIdx.x, tid = threadIdx.x;
    float cnt = (float)(gend[g] - gstart[g]);
    float inv = 1.f / fmaxf(cnt, 1.f);
    sx[tid]       = pooledSum[g * 512 + tid] * inv;
    sx[tid + 256] = pooledSum[g * 512 + 256 + tid] * inv;
    __syncthreads();

    float ai = bih0[tid]       + bhh0[tid];
    float ag = bih0[tid + 512] + bhh0[tid + 512];
    float ao = bih0[tid + 768] + bhh0[tid + 768];
    ai += dotf(Wih0 + (size_t)tid * 512, sx, 512);
    ag += dotf(Wih0 + (size_t)(tid + 512) * 512, sx, 512);
    ao += dotf(Wih0 + (size_t)(tid + 768) * 512, sx, 512);
    float c0 = sigm(ai) * tanhf(ag);
    float h1 = sigm(ao) * tanhf(c0);
    __syncthreads();
    sh[tid] = h1;
    __syncthreads();

    ai = bih1[tid]       + bhh1[tid];
    ag = bih1[tid + 512] + bhh1[tid + 512];
    ao = bih1[tid + 768] + bhh1[tid + 768];
    ai += dotf(Wih1 + (size_t)tid * 256, sh, 256);
    ag += dotf(Wih1 + (size_t)(tid + 512) * 256, sh, 256);
    ao += dotf(Wih1 + (size_t)(tid + 768) * 256, sh, 256);
    float c1 = sigm(ai) * tanhf(ag);
    float h2 = sigm(ao) * tanhf(c1);
    __syncthreads();
    sx[tid] = h2;
    __syncthreads();

    float o0 = bp[tid]       + dotf(Wp + (size_t)tid * 256, sx, 256);
    float o1 = bp[tid + 256] + dotf(Wp + (size_t)(tid + 256) * 256, sx, 256);
    out[g * 512 + tid]       = o0;
    out[g * 512 + 256 + tid] = o1;
}

// ---------------- launch ----------------

extern "C" void kernel_launch(void* const* d_in, const int* in_sizes, int n_in,
                              void* d_out, int out_size, void* d_ws, size_t ws_size,
                              hipStream_t stream) {
    const float* x     = (const float*)d_in[0];
    const int*   eidx  = (const int*)d_in[1];
    const int*   batch = (const int*)d_in[2];
    const float* W1 = (const float*)d_in[3];  const float* b1 = (const float*)d_in[4];
    const float* W2 = (const float*)d_in[5];  const float* b2 = (const float*)d_in[6];
    const float* W3 = (const float*)d_in[7];  const float* b3 = (const float*)d_in[8];
    const float* Wih0 = (const float*)d_in[9];
    const float* bih0 = (const float*)d_in[11];
    const float* bhh0 = (const float*)d_in[12];
    const float* Wih1 = (const float*)d_in[13];
    const float* bih1 = (const float*)d_in[15];
    const float* bhh1 = (const float*)d_in[16];
    const float* Wp = (const float*)d_in[17]; const float* bp = (const float*)d_in[18];
    float* out = (float*)d_out;

    const int N = in_sizes[0] / 32;
    const int E = in_sizes[1] / 2;
    const int* src = eidx;
    const int* dst = eidx + E;
    const int rowTiles = (N + 63) / 64;

    char* w = (char*)d_ws;
    auto alloc = [&](size_t bytes) {
        char* p = w;
        w += (bytes + 255) & ~(size_t)255;
        return p;
    };
    unsigned short* buf1 = (unsigned short*)alloc((size_t)N * 256 * 2);   // 51.2 MB
    unsigned short* buf2 = (unsigned short*)alloc((size_t)N * 256 * 2);   // 51.2 MB
    unsigned short* Wt1  = (unsigned short*)alloc(128 * 32 * 2);
    unsigned short* Wt2  = (unsigned short*)alloc(256 * 128 * 2);
    unsigned short* Wt3  = (unsigned short*)alloc(512 * 256 * 2);
    int*   indeg  = (int*)alloc((size_t)N * 4);
    int*   off    = (int*)alloc((size_t)(N + 1) * 4);
    int*   cursor = (int*)alloc((size_t)N * 4);
    float* dinv   = (float*)alloc((size_t)N * 4);
    int2*  cpack  = (int2*)alloc((size_t)E * 8);
    int*   bsum   = (int*)alloc(256 * 4);
    int*   gstart = (int*)alloc(64 * 4);
    int*   gend   = (int*)alloc(64 * 4);
    float* pooled = (float*)alloc(64 * 512 * 4);

    hipMemsetAsync(indeg, 0, (size_t)N * 4, stream);
    hipMemsetAsync(cursor, 0, (size_t)N * 4, stream);
    hipMemsetAsync(gstart, 0, 64 * 4, stream);
    hipMemsetAsync(gend, 0, 64 * 4, stream);
    hipMemsetAsync(pooled, 0, 64 * 512 * 4, stream);

    k_count<<<(E + 255) / 256, 256, 0, stream>>>(dst, indeg, E);
    int nb = (N + 1023) / 1024;
    k_scan1<<<nb, 1024, 0, stream>>>(indeg, off, bsum, dinv, N);
    k_scan2<<<1, 64, 0, stream>>>(bsum, nb);
    k_scan3<<<(N + 1 + 1023) / 1024, 1024, 0, stream>>>(off, bsum, N, nb);
    k_fill<<<(E + 255) / 256, 256, 0, stream>>>(src, dst, dinv, off, cursor, cpack, E);

    k_transpose<<<(32 * 128 + 255) / 256, 256, 0, stream>>>(W1, Wt1, 32, 128);
    k_transpose<<<(128 * 256 + 255) / 256, 256, 0, stream>>>(W2, Wt2, 128, 256);
    k_transpose<<<(256 * 512 + 255) / 256, 256, 0, stream>>>(W3, Wt3, 256, 512);
    k_bounds<<<(N + 255) / 256, 256, 0, stream>>>(batch, gstart, gend, N);

    int aggBlocks = (N + 3) / 4;                // one wave per node

    // layer 1: agg(x fp32 [N,32]) -> buf1; gemm -> buf2 [N,128]
    k_aggL1<<<aggBlocks, 256, 0, stream>>>(x, dinv, off, cpack, buf1, N);
    k_gemmL1<<<rowTiles, 256, 0, stream>>>(buf1, Wt1, b1, buf2, N);
    // layer 2: agg -> buf1 [N,128]; gemm -> buf2 [N,256]
    k_aggL2<<<aggBlocks, 256, 0, stream>>>(buf2, dinv, off, cpack, buf1, N);
    k_gemmL2<<<rowTiles, 256, 0, stream>>>(buf1, Wt2, b2, buf2, N);
    // layer 3: agg -> buf1 [N,256]; gemm fused relu+pool
    k_aggL3<<<aggBlocks, 256, 0, stream>>>(buf2, dinv, off, cpack, buf1, N);
    k_gemmL3pool<<<rowTiles, 256, 0, stream>>>(buf1, Wt3, b3, pooled, batch, N);

    k_head<<<64, 256, 0, stream>>>(pooled, gstart, gend,
                                   Wih0, bih0, bhh0, Wih1, bih1, bhh1, Wp, bp, out);
}